// Round 3
// baseline (47761.301 us; speedup 1.0000x reference)
//
#include <hip/hip_runtime.h>
#include <math.h>

#define BATCH 128
#define TSTEPS 256
#define CDIM 171
#define HID 1024
#define FOURH 4096
#define XSTR 6400          // 256 (padded x) + 6*1024 (h1,h1',h2,h2',h3,h3')
#define SEQB (TSTEPS*CDIM) // 43776 elements per batch row of seq/out

typedef short v8s __attribute__((ext_vector_type(8)));
typedef float v4f __attribute__((ext_vector_type(4)));

static __device__ __forceinline__ unsigned short f2bf(float f) {
  unsigned int u = __float_as_uint(f);
  u += 0x7fffu + ((u >> 16) & 1u);          // RTNE
  return (unsigned short)(u >> 16);
}
static __device__ __forceinline__ float bf2f(unsigned short h) {
  return __uint_as_float(((unsigned int)h) << 16);
}
static __device__ __forceinline__ float sigf(float x) { return 1.0f / (1.0f + expf(-x)); }

// dtype probe: if seq holds bf16 pairs, bits[14:7] of each u32 word are the
// bf16 exponent of the even element (always ~[90,145] for N(0,1) data); if
// genuine fp32, those are uniform mantissa bits (P(all 8 in range) ~ 5e-6).
static __device__ __forceinline__ bool probe_bf16(const unsigned int* w) {
  int c = 0;
  #pragma unroll
  for (int i = 0; i < 8; ++i) {
    unsigned e = (w[i] >> 7) & 0xFFu;
    c += (e >= 90u && e <= 145u) ? 1 : 0;
  }
  return c == 8;
}
static __device__ __forceinline__ float getv(const void* p, bool bf, size_t i) {
  return bf ? bf2f(((const unsigned short*)p)[i]) : ((const float*)p)[i];
}

// ---------------------------------------------------------------------------
// init: probe dtype; seed X (t=0 input, zero h banks), zero c, bias sums,
// convert/copy ALL weights into canonical bf16 ws buffers (exact round-trip
// when input is already bf16). w_ih1 zero-padded to [4096][256].
// ---------------------------------------------------------------------------
__global__ __launch_bounds__(256) void init_kernel(
    const void* seq, const void* wih1, const void* whh1,
    const void* bih1, const void* bhh1,
    const void* wih2, const void* whh2, const void* bih2, const void* bhh2,
    const void* wih3, const void* whh3, const void* bih3, const void* bhh3,
    const void* decw,
    unsigned short* __restrict__ X, float* __restrict__ Cst,
    float* __restrict__ bs, unsigned short* __restrict__ W1,
    unsigned short* __restrict__ H1, unsigned short* __restrict__ I2,
    unsigned short* __restrict__ H2, unsigned short* __restrict__ I3,
    unsigned short* __restrict__ H3, unsigned short* __restrict__ DW,
    const int* __restrict__ gtp, const int* __restrict__ condp)
{
  const int tid = blockIdx.x * 256 + threadIdx.x;
  const int NT = 512 * 256;
  const bool bf = probe_bf16((const unsigned int*)seq);
  int gt = gtp[0]; int per = gt + condp[0]; if (per < 1) per = 1;
  const bool p0 = (0 % per) < gt;

  for (int i = tid; i < BATCH * XSTR; i += NT) {
    int b = i / XSTR, c = i - b * XSTR;
    unsigned short v = 0;
    if (c < CDIM && p0) v = f2bf(getv(seq, bf, (size_t)b * SEQB + c));
    X[i] = v;
  }
  for (int i = tid; i < 3 * BATCH * HID; i += NT) Cst[i] = 0.f;
  const void* bis[3] = {bih1, bih2, bih3};
  const void* bhs[3] = {bhh1, bhh2, bhh3};
  for (int i = tid; i < 3 * FOURH; i += NT) {
    int l = i >> 12, n = i & 4095;
    bs[i] = getv(bis[l], bf, n) + getv(bhs[l], bf, n);
  }
  for (int i = tid; i < FOURH * 256; i += NT) {
    int n = i >> 8, c = i & 255;
    W1[i] = (c < CDIM) ? f2bf(getv(wih1, bf, (size_t)n * CDIM + c)) : (unsigned short)0;
  }
  auto conv = [&](unsigned short* dst, const void* src, int nelem) {
    for (int i = tid; i < nelem; i += NT) dst[i] = f2bf(getv(src, bf, i));
  };
  conv(H1, whh1, FOURH * HID);
  conv(I2, wih2, FOURH * HID);
  conv(H2, whh2, FOURH * HID);
  conv(I3, wih3, FOURH * HID);
  conv(H3, whh3, FOURH * HID);
  conv(DW, decw, CDIM * HID);
}

// ---------------------------------------------------------------------------
// Fused LSTM layer: z = A @ [B0|B1]^T (K-concat at b0c, A split at the same
// boundary: A0 = prev-layer activation, A1 = own h from bank p^1), then gate
// nonlinearity + cell update fused in registers. Grid 64 = 2 M-halves x 32
// h-col groups; block 256 = 4 waves, wave w owns rows [64m+16w,+16), full K.
// Gate fusion: acc nt=2q+s covers B rows 1024q+32n+16s+l15 -> all 4 gates of
// one (row,hcol) live in the same lane across acc[s],acc[2+s],acc[4+s],
// acc[6+s]; no reduction anywhere. Writes h into bank p (no intra-kernel
// read/write overlap -> race-free).
// ---------------------------------------------------------------------------
__global__ __launch_bounds__(256) void lstm_layer(
    unsigned short* X, int a0off, int a1off,
    const unsigned short* __restrict__ B0, int b0s, int b0c,
    const unsigned short* __restrict__ B1,
    const float* __restrict__ bs, float* __restrict__ Cst,
    int hoff, int nchunks)
{
  const int m = blockIdx.x >> 5;        // 0..1
  const int n = blockIdx.x & 31;        // h-cols [32n, 32n+32)
  const int wave = threadIdx.x >> 6, lane = threadIdx.x & 63;
  const int l15 = lane & 15, quad = lane >> 4;
  const size_t rowb = (size_t)(64 * m + 16 * wave + l15) * XSTR;
  const unsigned short* a0 = X + rowb + a0off + 8 * quad;
  const unsigned short* a1 = X + rowb + a1off + 8 * quad;

  int br[8];
  #pragma unroll
  for (int nt = 0; nt < 8; ++nt)
    br[nt] = 1024 * (nt >> 1) + 32 * n + 16 * (nt & 1) + l15;

  v4f acc[8];
  #pragma unroll
  for (int i = 0; i < 8; ++i) acc[i] = (v4f){0.f, 0.f, 0.f, 0.f};

  for (int c = 0; c < nchunks; ++c) {
    const int col = 32 * c;                       // wave-uniform
    const unsigned short* ap = (col < b0c) ? (a0 + col) : (a1 + (col - b0c));
    v8s a = *(const v8s*)ap;
    const unsigned short* bb; size_t bst;
    if (col < b0c) { bb = B0 + col + 8 * quad;         bst = (size_t)b0s; }
    else           { bb = B1 + (col - b0c) + 8 * quad; bst = 1024; }
    #pragma unroll
    for (int nt = 0; nt < 8; ++nt) {
      v8s b = *(const v8s*)(bb + (size_t)br[nt] * bst);
      acc[nt] = __builtin_amdgcn_mfma_f32_16x16x32_bf16(a, b, acc[nt], 0, 0, 0);
    }
  }

  // Epilogue: D layout col=lane&15 (h sub-col), row=4*quad+reg.
  #pragma unroll
  for (int s = 0; s < 2; ++s) {
    const int hcol = 32 * n + 16 * s + l15;
    const float bi = bs[hcol],        bfg = bs[1024 + hcol];
    const float bg = bs[2048 + hcol], bo  = bs[3072 + hcol];
    #pragma unroll
    for (int j = 0; j < 4; ++j) {
      const int row = 64 * m + 16 * wave + 4 * quad + j;
      float zi = acc[0 + s][j] + bi;
      float zf = acc[2 + s][j] + bfg;
      float zg = acc[4 + s][j] + bg;
      float zo = acc[6 + s][j] + bo;
      float cOld = Cst[row * 1024 + hcol];
      float cn = sigf(zf) * cOld + sigf(zi) * tanhf(zg);
      float h  = sigf(zo) * tanhf(cn);
      Cst[row * 1024 + hcol] = cn;
      X[(size_t)row * XSTR + hoff + hcol] = f2bf(h);
    }
  }
}

// ---------------------------------------------------------------------------
// decoder: out = h3 @ dec_w^T + dec_b; writes d_out[b][t][c] (dtype per
// probe) and the next step's auto-conditioned input into X. Grid 88 =
// 8 M-tiles x 11 N-tiles; 4 waves K-split 1024 -> 4x256, LDS reduce.
// ---------------------------------------------------------------------------
__global__ __launch_bounds__(256) void dec_kernel(
    unsigned short* X, int h3off,
    const unsigned short* __restrict__ DW, const void* __restrict__ decb,
    const void* __restrict__ seq, void* __restrict__ outp,
    int t, const int* __restrict__ gtp, const int* __restrict__ condp)
{
  const int mt = blockIdx.x / 11, nt = blockIdx.x % 11;
  const int wave = threadIdx.x >> 6, lane = threadIdx.x & 63;
  const int l15 = lane & 15, quad = lane >> 4;
  const int arow = 16 * mt + l15;
  int ncol = 16 * nt + l15; if (ncol > CDIM - 1) ncol = CDIM - 1; // clamp; store masked
  v4f acc = (v4f){0.f, 0.f, 0.f, 0.f};
  const int kb = wave * 256;
  #pragma unroll
  for (int c = 0; c < 8; ++c) {
    int kk = kb + 32 * c + 8 * quad;
    v8s a = *(const v8s*)(X + (size_t)arow * XSTR + h3off + kk);
    v8s b = *(const v8s*)(DW + (size_t)ncol * 1024 + kk);
    acc = __builtin_amdgcn_mfma_f32_16x16x32_bf16(a, b, acc, 0, 0, 0);
  }
  __shared__ float red[4][256];
  #pragma unroll
  for (int j = 0; j < 4; ++j) red[wave][lane * 4 + j] = acc[j];
  __syncthreads();
  if (wave == 0) {
    const bool bf = probe_bf16((const unsigned int*)seq);
    int gt = gtp[0]; int per = gt + condp[0]; if (per < 1) per = 1;
    const bool pnext = ((t + 1) % per) < gt;
    #pragma unroll
    for (int j = 0; j < 4; ++j) {
      float val = red[0][lane*4+j] + red[1][lane*4+j] + red[2][lane*4+j] + red[3][lane*4+j];
      int brow = 16 * mt + 4 * quad + j;
      int ccol = 16 * nt + l15;
      if (ccol < CDIM) {
        val += getv(decb, bf, ccol);
        size_t oidx = (size_t)brow * SEQB + (size_t)t * CDIM + ccol;
        if (bf) ((unsigned short*)outp)[oidx] = f2bf(val);
        else    ((float*)outp)[oidx] = val;
        if (t < TSTEPS - 1) {
          float xn = pnext ? getv(seq, bf, (size_t)brow * SEQB + (size_t)(t+1) * CDIM + ccol)
                           : val;
          X[(size_t)brow * XSTR + ccol] = f2bf(xn);
        }
      }
    }
  }
}

// ---------------------------------------------------------------------------
// Workspace (bytes, 256-aligned, total ~45.5 MB):
//   X   @ 0         : [128][6400] bf16 (x | h1_0 h1_1 h2_0 h2_1 h3_0 h3_1)
//   Cst @ 1638400   : [3][128][1024] fp32
//   BS  @ 3211264   : [3][4096] fp32
//   W1  @ 3260416   : [4096][256] bf16 (padded w_ih1)
//   WH1 @ 5357568   : [4096][1024] bf16
//   WI2 @ 13746176  : [4096][1024] bf16
//   WH2 @ 22134784  : [4096][1024] bf16
//   WI3 @ 30523392  : [4096][1024] bf16
//   WH3 @ 38912000  : [4096][1024] bf16
//   DW  @ 47300608  : [171][1024] bf16
// ---------------------------------------------------------------------------
extern "C" void kernel_launch(void* const* d_in, const int* in_sizes, int n_in,
                              void* d_out, int out_size, void* d_ws, size_t ws_size,
                              hipStream_t stream) {
  const void* seq  = d_in[0];
  const void* wih1 = d_in[1];  const void* whh1 = d_in[2];
  const void* bih1 = d_in[3];  const void* bhh1 = d_in[4];
  const void* wih2 = d_in[5];  const void* whh2 = d_in[6];
  const void* bih2 = d_in[7];  const void* bhh2 = d_in[8];
  const void* wih3 = d_in[9];  const void* whh3 = d_in[10];
  const void* bih3 = d_in[11]; const void* bhh3 = d_in[12];
  const void* decw = d_in[13]; const void* decb = d_in[14];
  const int* gtp   = (const int*)d_in[15];
  const int* condp = (const int*)d_in[16];

  char* ws = (char*)d_ws;
  unsigned short* X   = (unsigned short*)(ws + 0);
  float*          Cst = (float*)(ws + 1638400);
  float*          BS  = (float*)(ws + 3211264);
  unsigned short* W1  = (unsigned short*)(ws + 3260416);
  unsigned short* WH1 = (unsigned short*)(ws + 5357568);
  unsigned short* WI2 = (unsigned short*)(ws + 13746176);
  unsigned short* WH2 = (unsigned short*)(ws + 22134784);
  unsigned short* WI3 = (unsigned short*)(ws + 30523392);
  unsigned short* WH3 = (unsigned short*)(ws + 38912000);
  unsigned short* DW  = (unsigned short*)(ws + 47300608);

  init_kernel<<<512, 256, 0, stream>>>(seq, wih1, whh1, bih1, bhh1,
                                       wih2, whh2, bih2, bhh2,
                                       wih3, whh3, bih3, bhh3, decw,
                                       X, Cst, BS, W1, WH1, WI2, WH2, WI3, WH3, DW,
                                       gtp, condp);
  for (int t = 0; t < TSTEPS; ++t) {
    const int p = t & 1, q = p ^ 1;
    // L1: A = [x | h1(q)], K=1280; B = [W1pad | WH1]; writes h1(p)
    lstm_layer<<<64, 256, 0, stream>>>(X, 0, 256 + 1024*q, W1, 256, 256, WH1,
                                       BS, Cst, 256 + 1024*p, 40);
    // L2: A = [h1(p) | h2(q)], K=2048; B = [WI2 | WH2]; writes h2(p)
    lstm_layer<<<64, 256, 0, stream>>>(X, 256 + 1024*p, 2304 + 1024*q, WI2, 1024, 1024, WH2,
                                       BS + 4096, Cst + 131072, 2304 + 1024*p, 64);
    // L3: A = [h2(p) | h3(q)], K=2048; B = [WI3 | WH3]; writes h3(p)
    lstm_layer<<<64, 256, 0, stream>>>(X, 2304 + 1024*p, 4352 + 1024*q, WI3, 1024, 1024, WH3,
                                       BS + 8192, Cst + 262144, 4352 + 1024*p, 64);
    // Decoder reads h3(p); writes out[t] and next x
    dec_kernel<<<88, 256, 0, stream>>>(X, 4352 + 1024*p, DW, decb, seq, d_out,
                                       t, gtp, condp);
  }
}

// Round 5
// 39361.285 us; speedup vs baseline: 1.2134x; 1.2134x over previous
//
#include <hip/hip_runtime.h>
#include <math.h>

#define TSTEPS 256
#define CDIM 171
#define XSTR 6400          // 256 (padded x) + 6*1024 (h1,h1',h2,h2',h3,h3')
#define SEQB (TSTEPS*CDIM)

typedef short v8s __attribute__((ext_vector_type(8)));
typedef float v4f __attribute__((ext_vector_type(4)));

static __device__ __forceinline__ unsigned short f2bf(float f) {
  unsigned int u = __float_as_uint(f);
  u += 0x7fffu + ((u >> 16) & 1u);          // RTNE
  return (unsigned short)(u >> 16);
}
static __device__ __forceinline__ float bf2f(unsigned short h) {
  return __uint_as_float(((unsigned int)h) << 16);
}
static __device__ __forceinline__ float sigf(float x) { return 1.0f / (1.0f + expf(-x)); }

// dtype probe (verified in R3): bf16 pairs put a bf16 exponent in bits[14:7]
// of each u32; genuine fp32 puts uniform mantissa bits there.
static __device__ __forceinline__ bool probe_bf16(const unsigned int* w) {
  int c = 0;
  #pragma unroll
  for (int i = 0; i < 8; ++i) {
    unsigned e = (w[i] >> 7) & 0xFFu;
    c += (e >= 90u && e <= 145u) ? 1 : 0;
  }
  return c == 8;
}
static __device__ __forceinline__ float getv(const void* p, bool bf, size_t i) {
  return bf ? bf2f(((const unsigned short*)p)[i]) : ((const float*)p)[i];
}

// ---------------------------------------------------------------------------
// init: seed X, bias sums, zero barrier flags, repack ALL weights into
// K-concatenated canonical bf16 buffers:
//   WL1 [4096][1280] = [wih1 padded to 256 | whh1]
//   WL2/WL3 [4096][2048] = [wih | whh]
//   WDEC [176][1024] = dec_w zero-padded rows
// ---------------------------------------------------------------------------
__global__ __launch_bounds__(256) void init_kernel(
    const void* seq, const void* wih1, const void* whh1,
    const void* bih1, const void* bhh1,
    const void* wih2, const void* whh2, const void* bih2, const void* bhh2,
    const void* wih3, const void* whh3, const void* bih3, const void* bhh3,
    const void* decw,
    unsigned short* __restrict__ X, float* __restrict__ BS,
    unsigned* __restrict__ flags,
    unsigned short* __restrict__ WL1, unsigned short* __restrict__ WL2,
    unsigned short* __restrict__ WL3, unsigned short* __restrict__ WDEC,
    const int* __restrict__ gtp, const int* __restrict__ condp)
{
  const int tid = blockIdx.x * 256 + threadIdx.x;
  const int NT = 2048 * 256;
  const bool bfm = probe_bf16((const unsigned int*)seq);
  int gt = gtp[0];
  const bool p0 = 0 < gt;

  for (int i = tid; i < 128 * XSTR; i += NT) {
    int b = i / XSTR, c = i - b * XSTR;
    unsigned short v = 0;
    if (c < CDIM && p0) v = f2bf(getv(seq, bfm, (size_t)b * SEQB + c));
    X[i] = v;
  }
  const void* bis[3] = {bih1, bih2, bih3};
  const void* bhs[3] = {bhh1, bhh2, bhh3};
  for (int i = tid; i < 3 * 4096; i += NT) {
    int l = i >> 12, n = i & 4095;
    BS[i] = getv(bis[l], bfm, n) + getv(bhs[l], bfm, n);
  }
  for (int i = tid; i < 256; i += NT) flags[i] = 0u;
  for (int i = tid; i < 4096 * 1280; i += NT) {
    int r = i / 1280, c = i - r * 1280;
    float v;
    if (c < CDIM)      v = getv(wih1, bfm, (size_t)r * CDIM + c);
    else if (c < 256)  v = 0.f;
    else               v = getv(whh1, bfm, (size_t)r * 1024 + (c - 256));
    WL1[i] = f2bf(v);
  }
  for (int i = tid; i < 4096 * 2048; i += NT) {
    int r = i >> 11, c = i & 2047;
    size_t o = (size_t)r * 1024 + (c & 1023);
    WL2[i] = f2bf((c < 1024) ? getv(wih2, bfm, o) : getv(whh2, bfm, o));
    WL3[i] = f2bf((c < 1024) ? getv(wih3, bfm, o) : getv(whh3, bfm, o));
  }
  for (int i = tid; i < 176 * 1024; i += NT) {
    int r = i >> 10, c = i & 1023;
    WDEC[i] = (r < CDIM) ? f2bf(getv(decw, bfm, (size_t)r * 1024 + c)) : (unsigned short)0;
  }
}

// ---------------------------------------------------------------------------
// Grid barrier: flag-array + all-poll (no contended fetch_add). Thread0
// release-stores its WG's flag AFTER __syncthreads (whose implicit
// s_waitcnt vmcnt(0) drains all WG stores to L2); __threadfence gives the
// agent-scope L2 writeback for cross-XCD visibility. Wave0 polls all 256
// flags, 4 per lane. Works for any co-resident grid (256 WGs @ 1/CU here).
// ---------------------------------------------------------------------------
static __device__ __forceinline__ void gbar(unsigned* fl, int g, unsigned tgt,
                                            int wave, int lane) {
  __syncthreads();
  if (threadIdx.x == 0) {
    __threadfence();
    __hip_atomic_store(fl + g, tgt, __ATOMIC_RELEASE, __HIP_MEMORY_SCOPE_AGENT);
  }
  if (wave == 0) {
    for (;;) {
      unsigned a = __hip_atomic_load(fl + lane,       __ATOMIC_RELAXED, __HIP_MEMORY_SCOPE_AGENT);
      unsigned b = __hip_atomic_load(fl + 64 + lane,  __ATOMIC_RELAXED, __HIP_MEMORY_SCOPE_AGENT);
      unsigned c = __hip_atomic_load(fl + 128 + lane, __ATOMIC_RELAXED, __HIP_MEMORY_SCOPE_AGENT);
      unsigned d = __hip_atomic_load(fl + 192 + lane, __ATOMIC_RELAXED, __HIP_MEMORY_SCOPE_AGENT);
      if (__all((a >= tgt) & (b >= tgt) & (c >= tgt) & (d >= tgt))) break;
      __builtin_amdgcn_s_sleep(1);
    }
    if (lane == 0) __threadfence();
  }
  __syncthreads();
}

// MFMA phase: wave's K-slice against register-resident B frags, 8 M-tiles.
// A cols map through [a0 | a1] split at bnd (activation double-banking).
template<int NCH>
static __device__ __forceinline__ void mfma_phase(
    const v8s* wf, const unsigned short* __restrict__ Xb,
    int a0, int bnd, int a1, int kbase, v4f* acc)
{
  #pragma unroll
  for (int i = 0; i < 8; ++i) acc[i] = (v4f){0.f, 0.f, 0.f, 0.f};
  #pragma unroll
  for (int c = 0; c < NCH; ++c) {
    const int acol = kbase + 32 * c;
    const int xcol = (acol < bnd) ? (a0 + acol) : (a1 + acol - bnd);
    const unsigned short* ap = Xb + xcol;
    #pragma unroll
    for (int m = 0; m < 8; ++m) {
      v8s a = *(const v8s*)(ap + (size_t)(16 * m) * XSTR);
      acc[m] = __builtin_amdgcn_mfma_f32_16x16x32_bf16(a, wf[c], acc[m], 0, 0, 0);
    }
  }
}

// LDS 4-way K-reduce + register-local gate math + bf16 h store.
static __device__ __forceinline__ void lstm_epilogue(
    v4f* acc, float* lred, int wave, int lane,
    const float* bs4, float* cst2,
    unsigned short* __restrict__ X, int hoff, int g)
{
  const int l15 = lane & 15, quad = lane >> 4;
  float* myp = lred + wave * 2048;
  #pragma unroll
  for (int m = 0; m < 8; ++m)
    #pragma unroll
    for (int j = 0; j < 4; ++j)
      myp[m * 256 + (4 * quad + j) * 16 + l15] = acc[m][j];
  __syncthreads();
  const int ri = lane >> 2, hc = lane & 3;
  #pragma unroll
  for (int e = 0; e < 2; ++e) {
    const int m = 2 * wave + e;
    float z0 = bs4[0], z1 = bs4[1], z2 = bs4[2], z3 = bs4[3];
    #pragma unroll
    for (int w2 = 0; w2 < 4; ++w2) {
      const float* pp = lred + w2 * 2048 + m * 256 + ri * 16 + hc;
      z0 += pp[0]; z1 += pp[4]; z2 += pp[8]; z3 += pp[12];
    }
    float cn = sigf(z1) * cst2[e] + sigf(z0) * tanhf(z2);
    float h  = sigf(z3) * tanhf(cn);
    cst2[e] = cn;
    const int row = 32 * wave + 16 * e + ri;
    X[(size_t)row * XSTR + hoff + 4 * g + hc] = f2bf(h);
  }
  __syncthreads();   // lred reused next phase
}

// ---------------------------------------------------------------------------
// Persistent kernel (PLAIN launch; co-resident by construction: 32KB LDS,
// <=512 VGPR -> every CU hosts >=1 WG, grid 256 = capacity). WG g owns
// h-cols [4g,4g+4) of every layer (16 z-cols = 4 hcols x 4 gates; B-row for
// tile col n is 1024*(n>>2) + 4g + (n&3)). Waves K-split 4-way; all weights
// VGPR-resident (loaded once); c-state in registers; 4 barriers/timestep.
// ---------------------------------------------------------------------------
__global__ __launch_bounds__(256, 1) void persist(
    const unsigned short* __restrict__ WL1, const unsigned short* __restrict__ WL2,
    const unsigned short* __restrict__ WL3, const unsigned short* __restrict__ WDEC,
    const float* __restrict__ BS, unsigned short* __restrict__ X,
    unsigned* __restrict__ flags,
    const void* __restrict__ seq, const void* __restrict__ decb,
    void* __restrict__ outp, const int* __restrict__ gtp, const int* __restrict__ condp)
{
  const int g = blockIdx.x;
  const int tid = threadIdx.x, wave = tid >> 6, lane = tid & 63;
  const int l15 = lane & 15, quad = lane >> 4;
  const bool bf = probe_bf16((const unsigned int*)seq);
  int gt = gtp[0]; int per = gt + condp[0]; if (per < 1) per = 1;

  const int br = 1024 * (l15 >> 2) + 4 * g + (l15 & 3);
  v8s w1f[10], w2f[16], w3f[16], wdf[8];
  {
    const unsigned short* p = WL1 + (size_t)br * 1280 + 320 * wave + 8 * quad;
    #pragma unroll
    for (int c = 0; c < 10; ++c) w1f[c] = *(const v8s*)(p + 32 * c);
  }
  {
    const unsigned short* p = WL2 + (size_t)br * 2048 + 512 * wave + 8 * quad;
    #pragma unroll
    for (int c = 0; c < 16; ++c) w2f[c] = *(const v8s*)(p + 32 * c);
  }
  {
    const unsigned short* p = WL3 + (size_t)br * 2048 + 512 * wave + 8 * quad;
    #pragma unroll
    for (int c = 0; c < 16; ++c) w3f[c] = *(const v8s*)(p + 32 * c);
  }
  const int dm = g / 11, dn = g - dm * 11;
  if (g < 88) {
    const unsigned short* p = WDEC + (size_t)(16 * dn + l15) * 1024 + 256 * wave + 8 * quad;
    #pragma unroll
    for (int c = 0; c < 8; ++c) wdf[c] = *(const v8s*)(p + 32 * c);
  } else {
    #pragma unroll
    for (int c = 0; c < 8; ++c) wdf[c] = (v8s){0, 0, 0, 0, 0, 0, 0, 0};
  }
  float bsr[3][4];
  #pragma unroll
  for (int l = 0; l < 3; ++l)
    #pragma unroll
    for (int gm = 0; gm < 4; ++gm)
      bsr[l][gm] = BS[4096 * l + 1024 * gm + 4 * g + (lane & 3)];
  float dbv = 0.f;
  if (g < 88) { int col = 16 * dn + l15; if (col < CDIM) dbv = getv(decb, bf, col); }

  float cst1[2] = {0.f, 0.f}, cst2v[2] = {0.f, 0.f}, cst3[2] = {0.f, 0.f};
  __shared__ float lred[8192];                       // [4 waves][8 tiles][16][16]
  const unsigned short* Xb = X + (size_t)l15 * XSTR + 8 * quad;   // lane A-base
  unsigned bgen = 0;
  v4f acc[8];

  for (int t = 0; t < TSTEPS; ++t) {
    const int p_ = t & 1, q_ = p_ ^ 1;
    gbar(flags, g, ++bgen, wave, lane);              // dec(t-1) -> L1(t)
    mfma_phase<10>(w1f, Xb, 0, 256, 256 + 1024 * q_, 320 * wave, acc);
    lstm_epilogue(acc, lred, wave, lane, bsr[0], cst1, X, 256 + 1024 * p_, g);
    gbar(flags, g, ++bgen, wave, lane);
    mfma_phase<16>(w2f, Xb, 256 + 1024 * p_, 1024, 2304 + 1024 * q_, 512 * wave, acc);
    lstm_epilogue(acc, lred, wave, lane, bsr[1], cst2v, X, 2304 + 1024 * p_, g);
    gbar(flags, g, ++bgen, wave, lane);
    mfma_phase<16>(w3f, Xb, 2304 + 1024 * p_, 1024, 4352 + 1024 * q_, 512 * wave, acc);
    lstm_epilogue(acc, lred, wave, lane, bsr[2], cst3, X, 4352 + 1024 * p_, g);
    gbar(flags, g, ++bgen, wave, lane);              // L3 -> dec
    if (g < 88) {
      v4f da = (v4f){0.f, 0.f, 0.f, 0.f};
      const unsigned short* ap = X + (size_t)(16 * dm + l15) * XSTR
                               + (4352 + 1024 * p_) + 256 * wave + 8 * quad;
      #pragma unroll
      for (int c = 0; c < 8; ++c) {
        v8s a = *(const v8s*)(ap + 32 * c);
        da = __builtin_amdgcn_mfma_f32_16x16x32_bf16(a, wdf[c], da, 0, 0, 0);
      }
      float* myp = lred + wave * 2048;
      #pragma unroll
      for (int j = 0; j < 4; ++j) myp[(4 * quad + j) * 16 + l15] = da[j];
      __syncthreads();
      if (wave == 0) {
        const int col = 16 * dn + l15;
        const bool pnext = ((t + 1) % per) < gt;
        #pragma unroll
        for (int e = 0; e < 4; ++e) {
          const int r = 4 * e + quad;
          float v = dbv;
          #pragma unroll
          for (int w2 = 0; w2 < 4; ++w2) v += lred[w2 * 2048 + r * 16 + l15];
          if (col < CDIM) {
            const int brow = 16 * dm + r;
            const size_t oidx = (size_t)brow * SEQB + (size_t)t * CDIM + col;
            if (bf) ((unsigned short*)outp)[oidx] = f2bf(v);
            else    ((float*)outp)[oidx] = v;
            if (t < TSTEPS - 1) {
              float xn = pnext ? getv(seq, bf, (size_t)brow * SEQB + (size_t)(t + 1) * CDIM + col)
                               : v;
              X[(size_t)brow * XSTR + col] = f2bf(xn);
            }
          }
        }
      }
    }
  }
}

// ---------------------------------------------------------------------------
// Workspace (bytes, total ~46.1 MB):
//   X     @ 0         : [128][6400] bf16
//   BS    @ 1638400   : [3][4096] fp32
//   FLAGS @ 1687552   : [256] u32 barrier flags
//   WL1   @ 1690624   : [4096][1280] bf16
//   WL2   @ 12176384  : [4096][2048] bf16
//   WL3   @ 28953600  : [4096][2048] bf16
//   WDEC  @ 45730816  : [176][1024] bf16
// ---------------------------------------------------------------------------
extern "C" void kernel_launch(void* const* d_in, const int* in_sizes, int n_in,
                              void* d_out, int out_size, void* d_ws, size_t ws_size,
                              hipStream_t stream) {
  const void* seq  = d_in[0];
  const void* wih1 = d_in[1];  const void* whh1 = d_in[2];
  const void* bih1 = d_in[3];  const void* bhh1 = d_in[4];
  const void* wih2 = d_in[5];  const void* whh2 = d_in[6];
  const void* bih2 = d_in[7];  const void* bhh2 = d_in[8];
  const void* wih3 = d_in[9];  const void* whh3 = d_in[10];
  const void* bih3 = d_in[11]; const void* bhh3 = d_in[12];
  const void* decw = d_in[13]; const void* decb = d_in[14];
  const int* gtp   = (const int*)d_in[15];
  const int* condp = (const int*)d_in[16];

  char* ws = (char*)d_ws;
  unsigned short* X    = (unsigned short*)(ws + 0);
  float*          BS   = (float*)(ws + 1638400);
  unsigned*       FLAGS= (unsigned*)(ws + 1687552);
  unsigned short* WL1  = (unsigned short*)(ws + 1690624);
  unsigned short* WL2  = (unsigned short*)(ws + 12176384);
  unsigned short* WL3  = (unsigned short*)(ws + 28953600);
  unsigned short* WDEC = (unsigned short*)(ws + 45730816);

  init_kernel<<<2048, 256, 0, stream>>>(seq, wih1, whh1, bih1, bhh1,
                                        wih2, whh2, bih2, bhh2,
                                        wih3, whh3, bih3, bhh3, decw,
                                        X, BS, FLAGS, WL1, WL2, WL3, WDEC,
                                        gtp, condp);

  persist<<<256, 256, 0, stream>>>(WL1, WL2, WL3, WDEC, BS, X, FLAGS,
                                   seq, decb, d_out, gtp, condp);
}